// Round 4
// baseline (24.824 us; speedup 1.0000x reference)
//
#include <hip/hip_runtime.h>

// HeuristicBimodalCSRPool, two-pass:
//   Pass 1: per CSR segment, argmax (first index on ties) of x_proj[:,0]
//           -> idx to d_ws (int, -1 if empty), seen flag to out_seen.
//   Pass 2: gather x_mod[idx] (64 f32, float4 per lane over 16 lanes) -> out_pool.
// Splitting removes the 3-deep dependent-load chain of the fused version;
// each pass is a 1-2-deep chain running at its bandwidth ceiling.

typedef float f32x4 __attribute__((ext_vector_type(4)));

__global__ void __launch_bounds__(256)
argmax_kernel(const float* __restrict__ x_proj,
              const int* __restrict__ csr_idx,
              int* __restrict__ win_idx,
              float* __restrict__ out_seen,
              int n_groups, int n_elem) {
    const int lane16 = threadIdx.x & 15;
    const int g = blockIdx.x * 16 + (threadIdx.x >> 4);
    if (g >= n_groups) return;

    const int start = csr_idx[g];
    const int end   = csr_idx[g + 1];

    // Per-lane scan: max value, first index achieving it.
    float best = -__builtin_inff();
    int   bidx = n_elem;  // sentinel
    for (int e = start + lane16; e < end; e += 16) {
        float v = x_proj[(size_t)e * 8];      // FEAT = 0, N_PROJ = 8
        if (v > best) { best = v; bidx = e; } // per-lane ascending -> '>' keeps first
    }

    // 16-lane butterfly reduce: max value, min index on ties.
    #pragma unroll
    for (int off = 8; off >= 1; off >>= 1) {
        float ov = __shfl_xor(best, off);
        int   oi = __shfl_xor(bidx, off);
        if (ov > best || (ov == best && oi < bidx)) { best = ov; bidx = oi; }
    }

    if (lane16 == 0) {
        const bool seen = end > start;
        win_idx[g]  = seen ? bidx : -1;
        out_seen[g] = seen ? 1.0f : 0.0f;
    }
}

__global__ void __launch_bounds__(256)
gather_kernel(const float* __restrict__ x_mod,
              const int* __restrict__ win_idx,
              float* __restrict__ out_pool,
              int n_groups) {
    const int lane16 = threadIdx.x & 15;
    const int g = blockIdx.x * 16 + (threadIdx.x >> 4);
    if (g >= n_groups) return;

    const int row = win_idx[g];
    f32x4 v = {0.f, 0.f, 0.f, 0.f};
    if (row >= 0) {
        v = ((const f32x4*)x_mod)[(size_t)row * 16 + lane16];
    }
    ((f32x4*)out_pool)[(size_t)g * 16 + lane16] = v;
}

extern "C" void kernel_launch(void* const* d_in, const int* in_sizes, int n_in,
                              void* d_out, int out_size, void* d_ws, size_t ws_size,
                              hipStream_t stream) {
    // setup_inputs order: x_main (unused), x_mod, x_proj, csr_idx
    const float* x_mod  = (const float*)d_in[1];
    const float* x_proj = (const float*)d_in[2];
    const int*   csr    = (const int*)d_in[3];

    const int n_groups = in_sizes[3] - 1;     // csr_idx has n_groups+1 entries
    const int n_elem   = in_sizes[1] / 64;    // x_mod is (E, 64)

    float* out_pool = (float*)d_out;
    float* out_seen = out_pool + (size_t)n_groups * 64;
    int*   win_idx  = (int*)d_ws;             // n_groups ints (400 KB)

    dim3 block(256);
    dim3 grid((n_groups + 15) / 16);          // 16 groups per block
    argmax_kernel<<<grid, block, 0, stream>>>(x_proj, csr, win_idx, out_seen,
                                              n_groups, n_elem);
    gather_kernel<<<grid, block, 0, stream>>>(x_mod, win_idx, out_pool, n_groups);
}

// Round 5
// 20.295 us; speedup vs baseline: 1.2231x; 1.2231x over previous
//
#include <hip/hip_runtime.h>

// HeuristicBimodalCSRPool: per CSR segment, argmax (first index on ties) of
// x_proj[:, 0], gather that x_mod row (64 f32), plus a "seen" flag.
// 16 lanes per group, TWO groups per subgroup (fused scan loop -> 2 loads in
// flight per lane), 32 groups per 256-thread block. Row gather/write is one
// float4 per lane (coalesced 256 B per group).

typedef float f32x4 __attribute__((ext_vector_type(4)));

__global__ void __launch_bounds__(256)
csr_pool_kernel(const float* __restrict__ x_mod,
                const float* __restrict__ x_proj,
                const int* __restrict__ csr_idx,
                float* __restrict__ out_pool,
                float* __restrict__ out_seen,
                int n_groups, int n_elem) {
    const int lane16 = threadIdx.x & 15;
    const int sub = threadIdx.x >> 4;          // 0..15
    const int g0 = blockIdx.x * 32 + sub;      // first group of this subgroup
    const int g1 = g0 + 16;                    // second group
    if (g0 >= n_groups) return;
    const bool has1 = g1 < n_groups;

    const int s0 = csr_idx[g0];
    const int e0 = csr_idx[g0 + 1];
    int s1 = 0, e1 = 0;
    if (has1) { s1 = csr_idx[g1]; e1 = csr_idx[g1 + 1]; }

    // Fused dual scan: both groups' loads issue back-to-back each iteration.
    float b0 = -__builtin_inff(), b1 = -__builtin_inff();
    int   i0 = n_elem, i1 = n_elem;
    int   p0 = s0 + lane16, p1 = s1 + lane16;
    while (p0 < e0 || p1 < e1) {
        const bool a0 = p0 < e0, a1 = p1 < e1;
        float v0 = -__builtin_inff(), v1 = -__builtin_inff();
        if (a0) v0 = x_proj[(size_t)p0 * 8];   // FEAT = 0, N_PROJ = 8
        if (a1) v1 = x_proj[(size_t)p1 * 8];
        if (a0 && v0 > b0) { b0 = v0; i0 = p0; }  // per-lane ascending -> '>' keeps first
        if (a1 && v1 > b1) { b1 = v1; i1 = p1; }
        p0 += 16; p1 += 16;
    }

    // 16-lane butterfly reduce for both groups: max value, min index on ties.
    #pragma unroll
    for (int off = 8; off >= 1; off >>= 1) {
        float ov0 = __shfl_xor(b0, off);
        int   oi0 = __shfl_xor(i0, off);
        float ov1 = __shfl_xor(b1, off);
        int   oi1 = __shfl_xor(i1, off);
        if (ov0 > b0 || (ov0 == b0 && oi0 < i0)) { b0 = ov0; i0 = oi0; }
        if (ov1 > b1 || (ov1 == b1 && oi1 < i1)) { b1 = ov1; i1 = oi1; }
    }

    const bool seen0 = e0 > s0;
    const bool seen1 = e1 > s1;                // false when !has1 (s1==e1==0)

    // Issue both gathers before either store (2 loads in flight).
    f32x4 v0 = {0.f, 0.f, 0.f, 0.f}, v1 = {0.f, 0.f, 0.f, 0.f};
    if (seen0) v0 = ((const f32x4*)x_mod)[(size_t)i0 * 16 + lane16];
    if (seen1) v1 = ((const f32x4*)x_mod)[(size_t)i1 * 16 + lane16];

    ((f32x4*)out_pool)[(size_t)g0 * 16 + lane16] = v0;
    if (has1) ((f32x4*)out_pool)[(size_t)g1 * 16 + lane16] = v1;
    if (lane16 == 0) {
        out_seen[g0] = seen0 ? 1.0f : 0.0f;
        if (has1) out_seen[g1] = seen1 ? 1.0f : 0.0f;
    }
}

extern "C" void kernel_launch(void* const* d_in, const int* in_sizes, int n_in,
                              void* d_out, int out_size, void* d_ws, size_t ws_size,
                              hipStream_t stream) {
    // setup_inputs order: x_main (unused), x_mod, x_proj, csr_idx
    const float* x_mod  = (const float*)d_in[1];
    const float* x_proj = (const float*)d_in[2];
    const int*   csr    = (const int*)d_in[3];

    const int n_groups = in_sizes[3] - 1;     // csr_idx has n_groups+1 entries
    const int n_elem   = in_sizes[1] / 64;    // x_mod is (E, 64)

    float* out_pool = (float*)d_out;
    float* out_seen = out_pool + (size_t)n_groups * 64;

    const int groups_per_block = 32;          // 16 subgroups x 2 groups
    dim3 block(256);
    dim3 grid((n_groups + groups_per_block - 1) / groups_per_block);
    csr_pool_kernel<<<grid, block, 0, stream>>>(x_mod, x_proj, csr, out_pool,
                                                out_seen, n_groups, n_elem);
}